// Round 4
// baseline (2205.268 us; speedup 1.0000x reference)
//
#include <hip/hip_runtime.h>

typedef unsigned short u16;
typedef unsigned int u32;

using short8 = __attribute__((ext_vector_type(8))) short;
using f32x4  = __attribute__((ext_vector_type(4))) float;

#define LOG2E 1.44269504088896340736f

// X1 row: [h1_hi 0:128 | h1_lo 128:256 | x 256:272 | zero 272:288 | pad]
#define X1S 296
// H2 row: [h2_hi 0:64 | h2_lo 64:128 | pad]
#define H2S 136
#define DBS 40
#define W1XS 24    // Wih1 LDS row stride (u16), 512 gate-rows x 16 k

__device__ __forceinline__ u16 f2bf(float f) {
  u32 u = __float_as_uint(f);
  return (u16)((u + 0x7FFFu + ((u >> 16) & 1u)) >> 16);
}
__device__ __forceinline__ float bf2f(u16 h) {
  return __uint_as_float(((u32)h) << 16);
}
__device__ __forceinline__ float sigm(float x) {
  return __builtin_amdgcn_rcpf(1.0f + __builtin_amdgcn_exp2f(-LOG2E * x));
}
__device__ __forceinline__ float tanh_(float x) {
  return 1.0f - 2.0f * __builtin_amdgcn_rcpf(1.0f + __builtin_amdgcn_exp2f(2.0f * LOG2E * x));
}
__device__ __forceinline__ f32x4 mfma_(short8 a, short8 b, f32x4 c) {
  return __builtin_amdgcn_mfma_f32_16x16x32_bf16(a, b, c, 0, 0, 0);
}

// 1 block of 512 threads per CU; 2 waves/SIMD -> 256-VGPR cap (no spill).
__global__ __launch_bounds__(512, 1) void spc_lstm(
    const float* __restrict__ xh,   const float* __restrict__ xfr,
    const float* __restrict__ Wih1, const float* __restrict__ Whh1,
    const float* __restrict__ bih1, const float* __restrict__ bhh1,
    const float* __restrict__ Wih2, const float* __restrict__ Whh2,
    const float* __restrict__ bih2, const float* __restrict__ bhh2,
    const float* __restrict__ Wd,   const float* __restrict__ bd,
    const float* __restrict__ Wf,   const float* __restrict__ bfv,
    const float* __restrict__ ob,   float* __restrict__ out)
{
  __shared__ __align__(16) u16 X1[2][16 * X1S];      // 18944 B
  __shared__ __align__(16) u16 H2B[2][16 * H2S];     //  8704 B
  __shared__ __align__(16) u16 DB[16 * DBS];         //  1280 B
  __shared__ __align__(16) u16 Wih1L[512 * W1XS];    // 24576 B
  __shared__ u16 PREDV[16][2];

  const int tid = threadIdx.x;
  const int wv  = tid >> 6;          // 0..7
  const bool isA = (wv < 4);         // waves 0-3: L1 chain; 4-7: L2 + head
  const int wa  = wv;                // A wave id
  const int wb  = wv - 4;            // B wave id
  const int l   = tid & 63;
  const int c   = l & 15;            // MFMA n-col / A-row (batch)
  const int q   = l >> 4;
  const int bb  = blockIdx.x << 4;

  // register-resident weights
  short8 w1h[8][4];    // A: Whh1 fragments (128 VGPR)
  short8 w2ih[4][4];   // B: Wih2 fragments (64 VGPR)
  short8 w2h[4][2];    // B: Whh2 fragments (32 VGPR)
  short8 wdf[2];       // B (wb<2): Wd
  short8 wff;          // B (wb==0): Wf
  float  b1r[8], b2r[4], bdr = 0.f, bfr = 0.f;

  // ---- zero LDS regions that rely on zeros ----
  for (int i = tid; i < 2 * 16 * X1S; i += 512) ((u16*)X1)[i] = 0;
  for (int i = tid; i < 2 * 16 * H2S; i += 512) ((u16*)H2B)[i] = 0;
  for (int i = tid; i < 16 * DBS; i += 512) DB[i] = 0;
  if (tid < 32) ((u16*)PREDV)[tid] = 0;
  __syncthreads();

  // ---- Wih1 -> LDS (cooperative) ----
  for (int i = tid; i < 512 * 16; i += 512) {
    const int g = i >> 4, k = i & 15;
    Wih1L[g * W1XS + k] = f2bf(Wih1[g * 16 + k]);
  }

  // ---- register weights / biases ----
  if (isA) {
    #pragma unroll
    for (int nt = 0; nt < 8; nt++) {
      const int g = (nt >> 1) * 128 + wa * 32 + (nt & 1) * 16 + c;
      b1r[nt] = bih1[g] + bhh1[g];
      #pragma unroll
      for (int kc = 0; kc < 4; kc++) {
        short8 v;
        #pragma unroll
        for (int j = 0; j < 8; j++)
          v[j] = (short)f2bf(Whh1[g * 128 + kc * 32 + q * 8 + j]);
        w1h[nt][kc] = v;
      }
    }
  } else {
    #pragma unroll
    for (int nt = 0; nt < 4; nt++) {
      const int g = nt * 64 + wb * 16 + c;
      b2r[nt] = bih2[g] + bhh2[g];
      #pragma unroll
      for (int kc = 0; kc < 4; kc++) {
        short8 v;
        #pragma unroll
        for (int j = 0; j < 8; j++)
          v[j] = (short)f2bf(Wih2[g * 128 + kc * 32 + q * 8 + j]);
        w2ih[nt][kc] = v;
      }
      #pragma unroll
      for (int kc = 0; kc < 2; kc++) {
        short8 v;
        #pragma unroll
        for (int j = 0; j < 8; j++)
          v[j] = (short)f2bf(Whh2[g * 64 + kc * 32 + q * 8 + j]);
        w2h[nt][kc] = v;
      }
    }
    if (wb < 2) {
      const int g = wb * 16 + c;
      bdr = bd[g];
      #pragma unroll
      for (int kc = 0; kc < 2; kc++) {
        short8 v;
        #pragma unroll
        for (int j = 0; j < 8; j++)
          v[j] = (short)f2bf(Wd[g * 64 + kc * 32 + q * 8 + j]);
        wdf[kc] = v;
      }
    }
    if (wb == 0) {
      short8 v;
      #pragma unroll
      for (int j = 0; j < 8; j++)
        v[j] = (c < 2) ? (short)f2bf(Wf[c * 32 + q * 8 + j]) : (short)0;
      wff = v;
      bfr = (c < 2) ? (bfv[c] + ob[c]) : 0.f;
    }
  }

  // ---- stage x(0), prime x(1) (A threads) ----
  const int xr = tid >> 4, xcc = tid & 15;   // valid geometry for tid<256
  float xreg = 0.f; bool dreg = false;
  if (isA) {
    X1[0][xr * X1S + 256 + xcc] = f2bf(xh[(bb + xr) * 3200 + xcc]);
    xreg = xh[(bb + xr) * 3200 + 16 + xcc]; dreg = true;
  }
  f32x4 c1[2]; f32x4 c2;
  c1[0] = (f32x4){0,0,0,0}; c1[1] = (f32x4){0,0,0,0}; c2 = (f32x4){0,0,0,0};
  __syncthreads();

  // ==== pipelined loop: iteration t runs A:L1(t) and B:L2(t-1) ====
  for (int t = 0; t <= 220; t++) {
    const int p = t & 1;
    u16* Xc = X1[p];  u16* Xn = X1[p ^ 1];
    u16* Hc = H2B[p]; u16* Hn = H2B[p ^ 1];
    const bool dec  = (t >= 201);
    const bool actA = isA && (t < 220);
    const bool actB = (!isA) && (t >= 1);

    f32x4 acc[8];
    float xw = 0.f; bool dw = false;

    if (actA) {
      // x pipeline: xw = x(t+1); issue load of x(t+2)
      xw = xreg; dw = dreg;
      {
        const int s2 = t + 2;
        dreg = false;
        if (s2 < 200) { xreg = xh[(bb + xr) * 3200 + s2 * 16 + xcc]; dreg = true; }
        else if (s2 < 220) {
          const int s = s2 - 200;
          if (xcc < 14)    { xreg = xfr[(bb + xr) * 280 + s * 14 + xcc]; dreg = true; }
          else if (s == 0) { xreg = xh[(bb + xr) * 3200 + 199 * 16 + xcc]; dreg = true; }
        }
      }
      #pragma unroll
      for (int nt = 0; nt < 8; nt++)
        acc[nt] = (f32x4){b1r[nt], b1r[nt], b1r[nt], b1r[nt]};
      // pass 1: h1_hi
      short8 aH[4];
      #pragma unroll
      for (int kc = 0; kc < 4; kc++)
        aH[kc] = *(const short8*)&Xc[c * X1S + kc * 32 + q * 8];
      #pragma unroll
      for (int nt = 0; nt < 8; nt++)
        #pragma unroll
        for (int kc = 0; kc < 4; kc++)
          acc[nt] = mfma_(aH[kc], w1h[nt][kc], acc[nt]);
      // pass 2: h1_lo (same weights)
      #pragma unroll
      for (int kc = 0; kc < 4; kc++)
        aH[kc] = *(const short8*)&Xc[c * X1S + 128 + kc * 32 + q * 8];
      #pragma unroll
      for (int nt = 0; nt < 8; nt++)
        #pragma unroll
        for (int kc = 0; kc < 4; kc++)
          acc[nt] = mfma_(aH[kc], w1h[nt][kc], acc[nt]);
    }

    if (actB) {
      // L2 for step t-1: h1(t-1) from Xc, h2(t-2) from Hc
      short8 a2[12];
      #pragma unroll
      for (int kc = 0; kc < 8; kc++)
        a2[kc] = *(const short8*)&Xc[c * X1S + kc * 32 + q * 8];
      #pragma unroll
      for (int kc = 0; kc < 4; kc++)
        a2[8 + kc] = *(const short8*)&Hc[c * H2S + kc * 32 + q * 8];

      f32x4 acc2[4];
      #pragma unroll
      for (int nt = 0; nt < 4; nt++)
        acc2[nt] = (f32x4){b2r[nt], b2r[nt], b2r[nt], b2r[nt]};
      #pragma unroll
      for (int nt = 0; nt < 4; nt++) {
        #pragma unroll
        for (int kc = 0; kc < 4; kc++) {
          acc2[nt] = mfma_(a2[kc],     w2ih[nt][kc], acc2[nt]);
          acc2[nt] = mfma_(a2[4 + kc], w2ih[nt][kc], acc2[nt]);
        }
        #pragma unroll
        for (int kc = 0; kc < 2; kc++) {
          acc2[nt] = mfma_(a2[8 + kc],  w2h[nt][kc], acc2[nt]);
          acc2[nt] = mfma_(a2[10 + kc], w2h[nt][kc], acc2[nt]);
        }
      }
      // cell update + h2 hi/lo write -> Hn (= h2(t-1))
      const int u = wb * 16 + c;
      #pragma unroll
      for (int r = 0; r < 4; r++) {
        float ig = sigm(acc2[0][r]);
        float fg = sigm(acc2[1][r]);
        float gg = tanh_(acc2[2][r]);
        float og = sigm(acc2[3][r]);
        float cn = fg * c2[r] + ig * gg;
        float hn = og * tanh_(cn);
        c2[r] = cn;
        u16 hi = f2bf(hn);
        float lo = hn - bf2f(hi);
        const int row = (q * 4 + r) * H2S;
        Hn[row + u]      = hi;
        Hn[row + 64 + u] = f2bf(lo);
      }
    }

    if (dec) {
      __syncthreads();  // h2(t-1) visible
      if (!isA && wb < 2) {
        f32x4 accd = (f32x4){bdr, bdr, bdr, bdr};
        #pragma unroll
        for (int kc = 0; kc < 4; kc++) {
          const short8 ad = *(const short8*)&Hn[c * H2S + kc * 32 + q * 8];
          accd = mfma_(ad, wdf[kc & 1], accd);
        }
        #pragma unroll
        for (int r = 0; r < 4; r++)
          DB[(q * 4 + r) * DBS + wb * 16 + c] = f2bf(fmaxf(accd[r], 0.f));
      }
      __syncthreads();  // d visible
      if (!isA && wb == 0) {
        const short8 ap = *(const short8*)&DB[c * DBS + q * 8];
        f32x4 accp = (f32x4){bfr, bfr, bfr, bfr};
        accp = mfma_(ap, wff, accp);
        if (c < 2) {
          #pragma unroll
          for (int r = 0; r < 4; r++) {
            const int b = q * 4 + r;
            out[(bb + b) * 40 + (t - 201) * 2 + c] = accp[r];
            PREDV[b][c] = f2bf(accp[r]);     // pred(t-201) for A below
          }
        }
      }
      __syncthreads();  // pred visible
    }

    if (actA) {
      // pass 3: x row (+ pred feedback patch at decode)
      short8 ax = *(const short8*)&Xc[c * X1S + 256 + q * 8];
      if (dec && q == 1) {
        ax[6] = (short)PREDV[c][0];
        ax[7] = (short)PREDV[c][1];
      }
      #pragma unroll
      for (int nt = 0; nt < 8; nt++) {
        const int g = (nt >> 1) * 128 + wa * 32 + (nt & 1) * 16 + c;
        short8 wxv = (short8){0,0,0,0,0,0,0,0};
        if (q < 2) wxv = *(const short8*)&Wih1L[g * W1XS + q * 8];
        acc[nt] = mfma_(ax, wxv, acc[nt]);
      }
      // cell update + h1 hi/lo write -> Xn (= h1(t))
      #pragma unroll
      for (int sub = 0; sub < 2; sub++) {
        const int u = wa * 32 + sub * 16 + c;
        #pragma unroll
        for (int r = 0; r < 4; r++) {
          float ig = sigm(acc[sub][r]);
          float fg = sigm(acc[2 + sub][r]);
          float gg = tanh_(acc[4 + sub][r]);
          float og = sigm(acc[6 + sub][r]);
          float cn = fg * c1[sub][r] + ig * gg;
          float hn = og * tanh_(cn);
          c1[sub][r] = cn;
          u16 hi = f2bf(hn);
          float lo = hn - bf2f(hi);
          const int row = (q * 4 + r) * X1S;
          Xn[row + u]       = hi;
          Xn[row + 128 + u] = f2bf(lo);
        }
      }
      if (dw) Xn[xr * X1S + 256 + xcc] = f2bf(xw);   // stage x(t+1)
    }
    __syncthreads();  // end-of-step: Xn/Hn published
  }
}

extern "C" void kernel_launch(void* const* d_in, const int* in_sizes, int n_in,
                              void* d_out, int out_size, void* d_ws, size_t ws_size,
                              hipStream_t stream) {
  (void)in_sizes; (void)n_in; (void)out_size; (void)d_ws; (void)ws_size;
  spc_lstm<<<dim3(256), dim3(512), 0, stream>>>(
      (const float*)d_in[0],  (const float*)d_in[1],
      (const float*)d_in[2],  (const float*)d_in[3],
      (const float*)d_in[4],  (const float*)d_in[5],
      (const float*)d_in[6],  (const float*)d_in[7],
      (const float*)d_in[8],  (const float*)d_in[9],
      (const float*)d_in[10], (const float*)d_in[11],
      (const float*)d_in[12], (const float*)d_in[13],
      (const float*)d_in[14], (float*)d_out);
}

// Round 5
// 675.866 us; speedup vs baseline: 3.2629x; 3.2629x over previous
//
#include <hip/hip_runtime.h>

typedef unsigned short u16;
typedef unsigned int u32;

using short8 = __attribute__((ext_vector_type(8))) short;
using f32x4  = __attribute__((ext_vector_type(4))) float;

#define LOG2E 1.44269504088896340736f

// Activation layouts (16B-aligned strides, same as the passing R2 kernel):
// X1 row (per batch): [h1_hi 0:128 | h1_lo 128:256 | x 256:272 | zeros 272:288 | pad]
#define X1S 296
// H2 row: [h2_hi 0:64 | h2_lo 64:128 | pad]
#define H2S 136
#define DBS 40

__device__ __forceinline__ u16 f2bf(float f) {
  u32 u = __float_as_uint(f);
  return (u16)((u + 0x7FFFu + ((u >> 16) & 1u)) >> 16);
}
__device__ __forceinline__ float bf2f(u16 h) {
  return __uint_as_float(((u32)h) << 16);
}
__device__ __forceinline__ float sigm(float x) {
  return __builtin_amdgcn_rcpf(1.0f + __builtin_amdgcn_exp2f(-LOG2E * x));
}
__device__ __forceinline__ float tanh_(float x) {
  return 1.0f - 2.0f * __builtin_amdgcn_rcpf(1.0f + __builtin_amdgcn_exp2f(2.0f * LOG2E * x));
}
__device__ __forceinline__ f32x4 mfma_(short8 a, short8 b, f32x4 c) {
  return __builtin_amdgcn_mfma_f32_16x16x32_bf16(a, b, c, 0, 0, 0);
}

// 256 threads, 1 wave/SIMD: the only config confirmed to give the full
// 256-arch-VGPR budget (R2). Weights beyond Whh1/Whh2 live in LDS as
// fragment-linear tiles (base + lane*16B -> conflict-free b128 reads).
__global__ __launch_bounds__(256, 1) void spc_lstm(
    const float* __restrict__ xh,   const float* __restrict__ xfr,
    const float* __restrict__ Wih1, const float* __restrict__ Whh1,
    const float* __restrict__ bih1, const float* __restrict__ bhh1,
    const float* __restrict__ Wih2, const float* __restrict__ Whh2,
    const float* __restrict__ bih2, const float* __restrict__ bhh2,
    const float* __restrict__ Wd,   const float* __restrict__ bd,
    const float* __restrict__ Wf,   const float* __restrict__ bfv,
    const float* __restrict__ ob,   float* __restrict__ out)
{
  __shared__ __align__(16) u16 X1[2][16 * X1S];   // 18944 B
  __shared__ __align__(16) u16 H2B[2][16 * H2S];  //  8704 B
  __shared__ __align__(16) u16 DB[16 * DBS];      //  1280 B
  __shared__ __align__(16) u16 W1xF[32 * 512];    // 32768 B  Wih1 x-frags (zeros k>=16)
  __shared__ __align__(16) u16 W2F[64 * 512];     // 65536 B  Wih2 frags
  __shared__ __align__(16) u16 WdF[4 * 512];      //  4096 B
  __shared__ __align__(16) u16 WfF[512];          //  1024 B  (zeros n>=2)
  __shared__ u16 PREDV[16][2];
  // total ~132.4 KB

  const int tid = threadIdx.x;
  const int w   = tid >> 6;   // wave 0..3
  const int l   = tid & 63;
  const int c   = l & 15;     // MFMA col (gate) for C-layout; batch row for A-frags
  const int q   = l >> 4;
  const int bb  = blockIdx.x << 4;

  // register-resident recurrent weights only
  short8 w1h[8][4];   // Whh1 (128 VGPR)
  short8 w2h[4][2];   // Whh2 (32 VGPR)
  float  b1r[8], b2r[4];

  // ---- zero activation LDS ----
  for (int i = tid; i < 2 * 16 * X1S; i += 256) ((u16*)X1)[i] = 0;
  for (int i = tid; i < 2 * 16 * H2S; i += 256) ((u16*)H2B)[i] = 0;
  for (int i = tid; i < 16 * DBS; i += 256) DB[i] = 0;
  if (tid < 32) ((u16*)PREDV)[tid] = 0;
  __syncthreads();

  // ---- weight LDS fills (fragment-linear: elem (k,n) -> ((k>>3)*16+n)*8 + (k&7)) ----
  for (int i = tid; i < 64 * 512; i += 256) {         // Wih2: tile rid=(w,nt,kc)
    const int rid = i >> 9, e = i & 511, k = e >> 4, n = e & 15;
    const int ww = rid >> 4, nt = (rid >> 2) & 3, kc = rid & 3;
    const int g = nt * 64 + ww * 16 + n;
    W2F[rid * 512 + ((k >> 3) * 16 + n) * 8 + (k & 7)] = f2bf(Wih2[g * 128 + kc * 32 + k]);
  }
  for (int i = tid; i < 32 * 512; i += 256) {         // Wih1 x-frags: tile tix=(w,nt)
    const int tix = i >> 9, e = i & 511, k = e >> 4, n = e & 15;
    const int ww = tix >> 3, nt = tix & 7;
    const int g = (nt >> 1) * 128 + ww * 32 + (nt & 1) * 16 + n;
    W1xF[tix * 512 + ((k >> 3) * 16 + n) * 8 + (k & 7)] =
        (k < 16) ? f2bf(Wih1[g * 16 + k]) : (u16)0;
  }
  for (int i = tid; i < 4 * 512; i += 256) {          // Wd: tile tix=(w01,kc2)
    const int tix = i >> 9, e = i & 511, k = e >> 4, n = e & 15;
    const int ww = tix >> 1, kc2 = tix & 1;
    WdF[tix * 512 + ((k >> 3) * 16 + n) * 8 + (k & 7)] =
        f2bf(Wd[(ww * 16 + n) * 64 + kc2 * 32 + k]);
  }
  for (int i = tid; i < 512; i += 256) {              // Wf (zeros for n>=2)
    const int k = i >> 4, n = i & 15;
    WfF[((k >> 3) * 16 + n) * 8 + (k & 7)] = (n < 2) ? f2bf(Wf[n * 32 + k]) : (u16)0;
  }

  // ---- register weights / biases (all waves uniform role, as R2) ----
  #pragma unroll
  for (int nt = 0; nt < 8; nt++) {
    const int g = (nt >> 1) * 128 + w * 32 + (nt & 1) * 16 + c;
    b1r[nt] = bih1[g] + bhh1[g];
    #pragma unroll
    for (int kc = 0; kc < 4; kc++) {
      short8 v;
      #pragma unroll
      for (int j = 0; j < 8; j++)
        v[j] = (short)f2bf(Whh1[g * 128 + kc * 32 + q * 8 + j]);
      w1h[nt][kc] = v;
    }
  }
  #pragma unroll
  for (int nt = 0; nt < 4; nt++) {
    const int g = nt * 64 + w * 16 + c;
    b2r[nt] = bih2[g] + bhh2[g];
    #pragma unroll
    for (int kc = 0; kc < 2; kc++) {
      short8 v;
      #pragma unroll
      for (int j = 0; j < 8; j++)
        v[j] = (short)f2bf(Whh2[g * 64 + kc * 32 + q * 8 + j]);
      w2h[nt][kc] = v;
    }
  }
  const float bdr = (w < 2) ? bd[w * 16 + c] : 0.f;
  const float bfr = (w == 0 && c < 2) ? (bfv[c] + ob[c]) : 0.f;

  // ---- stage x(0), prime x(1) ----
  const int xr = tid >> 4, xcc = tid & 15;
  X1[0][xr * X1S + 256 + xcc] = f2bf(xh[(bb + xr) * 3200 + xcc]);
  float xreg = xh[(bb + xr) * 3200 + 16 + xcc];
  bool  dreg = true;

  f32x4 c1[2]; f32x4 c2;
  c1[0] = (f32x4){0,0,0,0}; c1[1] = (f32x4){0,0,0,0}; c2 = (f32x4){0,0,0,0};
  __syncthreads();

  for (int t = 0; t < 220; t++) {
    const int p = t & 1;
    u16* Xc = X1[p];  u16* Xn = X1[p ^ 1];
    u16* Hc = H2B[p]; u16* Hn = H2B[p ^ 1];
    const bool dec = (t >= 201);

    // x pipeline: xw = x(t+1) (loaded at t-1); issue load of x(t+2)
    const float xw = xreg; const bool dw = dreg;
    {
      const int s2 = t + 2;
      dreg = false;
      if (s2 < 200) { xreg = xh[(bb + xr) * 3200 + s2 * 16 + xcc]; dreg = true; }
      else if (s2 < 220) {
        const int s = s2 - 200;
        if (xcc < 14)    { xreg = xfr[(bb + xr) * 280 + s * 14 + xcc]; dreg = true; }
        else if (s == 0) { xreg = xh[(bb + xr) * 3200 + 199 * 16 + xcc]; dreg = true; }
      }
    }

    // ---- L1: acc = bias; stream kc chunks (hi+lo share w1h) ----
    f32x4 acc[8];
    #pragma unroll
    for (int nt = 0; nt < 8; nt++)
      acc[nt] = (f32x4){b1r[nt], b1r[nt], b1r[nt], b1r[nt]};
    #pragma unroll
    for (int kc = 0; kc < 4; kc++) {
      const short8 ahi = *(const short8*)&Xc[c * X1S + kc * 32 + q * 8];
      const short8 alo = *(const short8*)&Xc[c * X1S + 128 + kc * 32 + q * 8];
      #pragma unroll
      for (int nt = 0; nt < 8; nt++) {
        acc[nt] = mfma_(ahi, w1h[nt][kc], acc[nt]);
        acc[nt] = mfma_(alo, w1h[nt][kc], acc[nt]);
      }
    }
    // x pass: weights from LDS frag tiles (zeros baked for k>=16)
    {
      short8 ax = *(const short8*)&Xc[c * X1S + 256 + q * 8];
      if (dec && q == 1) {                 // pred feedback: features 14,15
        ax[6] = (short)PREDV[c][0];
        ax[7] = (short)PREDV[c][1];
      }
      #pragma unroll
      for (int nt = 0; nt < 8; nt++) {
        const short8 wxv = *(const short8*)&W1xF[(w * 8 + nt) * 512 + l * 8];
        acc[nt] = mfma_(ax, wxv, acc[nt]);
      }
    }

    // ---- L1 cell update + h1 hi/lo write ----
    #pragma unroll
    for (int sub = 0; sub < 2; sub++) {
      const int u = w * 32 + sub * 16 + c;
      #pragma unroll
      for (int r = 0; r < 4; r++) {
        float ig = sigm(acc[sub][r]);
        float fg = sigm(acc[2 + sub][r]);
        float gg = tanh_(acc[4 + sub][r]);
        float og = sigm(acc[6 + sub][r]);
        float cn = fg * c1[sub][r] + ig * gg;
        float hn = og * tanh_(cn);
        c1[sub][r] = cn;
        u16 hi = f2bf(hn);
        float lo = hn - bf2f(hi);
        const int row = (q * 4 + r) * X1S;
        Xn[row + u]       = hi;
        Xn[row + 128 + u] = f2bf(lo);
      }
    }
    if (dw) Xn[xr * X1S + 256 + xcc] = f2bf(xw);   // stage x(t+1)

    __syncthreads();  // h1_t visible

    // ---- L2: gates = Wih2@h1(hi+lo) + Whh2@h2(hi+lo) ----
    f32x4 acc2[4];
    #pragma unroll
    for (int nt = 0; nt < 4; nt++)
      acc2[nt] = (f32x4){b2r[nt], b2r[nt], b2r[nt], b2r[nt]};
    #pragma unroll
    for (int kc = 0; kc < 4; kc++) {
      const short8 ahi = *(const short8*)&Xn[c * X1S + kc * 32 + q * 8];
      const short8 alo = *(const short8*)&Xn[c * X1S + 128 + kc * 32 + q * 8];
      #pragma unroll
      for (int nt = 0; nt < 4; nt++) {
        const short8 wf_ = *(const short8*)&W2F[(w * 16 + nt * 4 + kc) * 512 + l * 8];
        acc2[nt] = mfma_(ahi, wf_, acc2[nt]);
        acc2[nt] = mfma_(alo, wf_, acc2[nt]);
      }
    }
    #pragma unroll
    for (int kc = 0; kc < 2; kc++) {
      const short8 hhi = *(const short8*)&Hc[c * H2S + kc * 32 + q * 8];
      const short8 hlo = *(const short8*)&Hc[c * H2S + 64 + kc * 32 + q * 8];
      #pragma unroll
      for (int nt = 0; nt < 4; nt++) {
        acc2[nt] = mfma_(hhi, w2h[nt][kc], acc2[nt]);
        acc2[nt] = mfma_(hlo, w2h[nt][kc], acc2[nt]);
      }
    }

    // ---- L2 cell update + h2 hi/lo write ----
    {
      const int u = w * 16 + c;
      #pragma unroll
      for (int r = 0; r < 4; r++) {
        float ig = sigm(acc2[0][r]);
        float fg = sigm(acc2[1][r]);
        float gg = tanh_(acc2[2][r]);
        float og = sigm(acc2[3][r]);
        float cn = fg * c2[r] + ig * gg;
        float hn = og * tanh_(cn);
        c2[r] = cn;
        u16 hi = f2bf(hn);
        float lo = hn - bf2f(hi);
        const int row = (q * 4 + r) * H2S;
        Hn[row + u]      = hi;
        Hn[row + 64 + u] = f2bf(lo);
      }
    }

    // ---- decoder head ----
    if (t >= 200) {
      __syncthreads();  // h2_t visible
      if (w < 2) {
        f32x4 accd = (f32x4){bdr, bdr, bdr, bdr};
        #pragma unroll
        for (int kc = 0; kc < 4; kc++) {
          const short8 ad  = *(const short8*)&Hn[c * H2S + kc * 32 + q * 8];
          const short8 wdk = *(const short8*)&WdF[(w * 2 + (kc & 1)) * 512 + l * 8];
          accd = mfma_(ad, wdk, accd);
        }
        #pragma unroll
        for (int r = 0; r < 4; r++)
          DB[(q * 4 + r) * DBS + w * 16 + c] = f2bf(fmaxf(accd[r], 0.f));
      }
      __syncthreads();  // d visible
      if (w == 0) {
        const short8 ap  = *(const short8*)&DB[c * DBS + q * 8];
        const short8 wfv = *(const short8*)&WfF[l * 8];
        f32x4 accp = (f32x4){bfr, bfr, bfr, bfr};
        accp = mfma_(ap, wfv, accp);
        if (c < 2) {
          #pragma unroll
          for (int r = 0; r < 4; r++) {
            const int b = q * 4 + r;
            out[(bb + b) * 40 + (t - 200) * 2 + c] = accp[r];
            PREDV[b][c] = f2bf(accp[r]);     // consumed at step t+1
          }
        }
      }
    }
    __syncthreads();  // end-of-step: Xn/Hn/PREDV published
  }
}

extern "C" void kernel_launch(void* const* d_in, const int* in_sizes, int n_in,
                              void* d_out, int out_size, void* d_ws, size_t ws_size,
                              hipStream_t stream) {
  (void)in_sizes; (void)n_in; (void)out_size; (void)d_ws; (void)ws_size;
  spc_lstm<<<dim3(256), dim3(256), 0, stream>>>(
      (const float*)d_in[0],  (const float*)d_in[1],
      (const float*)d_in[2],  (const float*)d_in[3],
      (const float*)d_in[4],  (const float*)d_in[5],
      (const float*)d_in[6],  (const float*)d_in[7],
      (const float*)d_in[8],  (const float*)d_in[9],
      (const float*)d_in[10], (const float*)d_in[11],
      (const float*)d_in[12], (const float*)d_in[13],
      (const float*)d_in[14], (float*)d_out);
}